// Round 14
// baseline (366.732 us; speedup 1.0000x reference)
//
#include <hip/hip_runtime.h>
#include <hip/hip_bf16.h>

#define D 128

typedef __attribute__((ext_vector_type(8))) short bfrag;   // 8 bf16 (4 VGPRs)
typedef __attribute__((ext_vector_type(4))) float facc;    // 4 f32 acc
typedef __attribute__((ext_vector_type(4))) unsigned int u32x4;
typedef __attribute__((ext_vector_type(4))) float f32x4;

__device__ __forceinline__ facc mfma16(bfrag a, bfrag b, facc c) {
    return __builtin_amdgcn_mfma_f32_16x16x32_bf16(a, b, c, 0, 0, 0);
}
__device__ __forceinline__ unsigned int bf16_rn(float f) {
    unsigned int u = __float_as_uint(f);
    u += 0x7FFF + ((u >> 16) & 1);   // round-nearest-even
    return u >> 16;
}
__device__ __forceinline__ float bf16_f(unsigned int h) {
    return __uint_as_float(h << 16);
}
// pack f32 -> (bf16_hi << 16) | bf16_lo
__device__ __forceinline__ unsigned int packf(float v) {
    unsigned int hi = bf16_rn(v);
    unsigned int lo = bf16_rn(v - bf16_f(hi));
    return (hi << 16) | lo;
}
// split 8 packed u32 -> bf16 hi/lo fragments (k-order preserved)
__device__ __forceinline__ void splitA(const unsigned int ua[8], bfrag& ah,
                                       bfrag& al) {
    u32x4 uh, ul;
#pragma unroll
    for (int r = 0; r < 4; ++r) {
        uh[r] = __builtin_amdgcn_perm(ua[2 * r + 1], ua[2 * r], 0x07060302u);
        ul[r] = __builtin_amdgcn_perm(ua[2 * r + 1], ua[2 * r], 0x05040100u);
    }
    ah = __builtin_bit_cast(bfrag, uh);
    al = __builtin_bit_cast(bfrag, ul);
}

// ---------------------------------------------------------------------------
// Histogram of edge source nodes.
// ---------------------------------------------------------------------------
__global__ __launch_bounds__(256) void hist_kernel(
    const int* __restrict__ src, int* __restrict__ counts, int nedges) {
    int e = blockIdx.x * 256 + threadIdx.x;
    if (e < nedges) atomicAdd(&counts[src[e]], 1);
}

// ---------------------------------------------------------------------------
// Single-dispatch exclusive scan of counts[n] -> off[n+1], cur[n].
// 25 co-resident blocks; device-scope arrival counter + spin.
// ---------------------------------------------------------------------------
#define SCHUNK 2048
__global__ __launch_bounds__(256) void scanF_kernel(
    const int* __restrict__ counts, int* __restrict__ bsum,
    int* __restrict__ ctr, int* __restrict__ off, int* __restrict__ cur,
    int n, int nbk) {
    __shared__ int sd[256];
    __shared__ int sbase;
    const int tid = threadIdx.x;
    const int b = blockIdx.x;
    const int base = b * SCHUNK + tid * 8;
    int loc[8];
    int s = 0;
#pragma unroll
    for (int j = 0; j < 8; ++j) {
        int idx = base + j;
        int c = (idx < n) ? counts[idx] : 0;
        loc[j] = c;
        s += c;
    }
    sd[tid] = s;
    __syncthreads();
#pragma unroll
    for (int d2 = 1; d2 < 256; d2 <<= 1) {
        int t = (tid >= d2) ? sd[tid - d2] : 0;
        __syncthreads();
        sd[tid] += t;
        __syncthreads();
    }
    if (tid == 0) {
        atomicExch(&bsum[b], sd[255]);
        __threadfence();
        atomicAdd(ctr, 1);
        while (atomicAdd(ctr, 0) < nbk) __builtin_amdgcn_s_sleep(8);
    }
    __syncthreads();
    if (tid < 64) {
        int t = (tid < b) ? atomicAdd(&bsum[tid], 0) : 0;
#pragma unroll
        for (int o = 32; o; o >>= 1) t += __shfl_down(t, o);
        if (tid == 0) sbase = t;
    }
    __syncthreads();
    int pre = sbase + sd[tid] - s;
#pragma unroll
    for (int j = 0; j < 8; ++j) {
        int idx = base + j;
        if (idx < n) {
            off[idx] = pre;
            cur[idx] = pre;
            pre += loc[j];
        }
    }
    if (b == nbk - 1 && tid == 0) off[n] = sbase + sd[255];
}

// ---------------------------------------------------------------------------
// CSR fill: bin edge ids by source node.
// ---------------------------------------------------------------------------
__global__ void fill_kernel(const int* __restrict__ src, int* __restrict__ cur,
                            int* __restrict__ eid, int nedges) {
    int e = blockIdx.x * 256 + threadIdx.x;
    if (e < nedges) {
        int slot = atomicAdd(&cur[src[e]], 1);
        eid[slot] = e;
    }
}

// ---------------------------------------------------------------------------
// Fused gather + x-split + W1-prep (R13 structure, unchanged).
// Gather: one half-wave (32 lanes x 16B = 512B) per node, 8-deep batches.
// ---------------------------------------------------------------------------
__global__ __launch_bounds__(256) void gather_split_kernel(
    const float* __restrict__ edge_attr, const int* __restrict__ eid,
    const int* __restrict__ off, unsigned int* __restrict__ aggp, int nnodes,
    const float* __restrict__ x, unsigned int* __restrict__ xp, int n4,
    const float* __restrict__ W1, unsigned short* __restrict__ Wh,
    unsigned short* __restrict__ Wl, int gblk, int sblk) {
    const int b = blockIdx.x;
    if (b < gblk) {
        int node = b * 8 + (threadIdx.x >> 5);   // half-wave per node
        if (node >= nnodes) return;
        const int c = threadIdx.x & 31;
        int i = off[node];
        const int e = off[node + 1];
        f32x4 acc = {0.f, 0.f, 0.f, 0.f};

        for (; i + 8 <= e; i += 8) {
            int r0 = eid[i + 0], r1 = eid[i + 1], r2 = eid[i + 2],
                r3 = eid[i + 3], r4 = eid[i + 4], r5 = eid[i + 5],
                r6 = eid[i + 6], r7 = eid[i + 7];
            f32x4 v0 = __builtin_nontemporal_load(
                (const f32x4*)(edge_attr + (size_t)r0 * D) + c);
            f32x4 v1 = __builtin_nontemporal_load(
                (const f32x4*)(edge_attr + (size_t)r1 * D) + c);
            f32x4 v2 = __builtin_nontemporal_load(
                (const f32x4*)(edge_attr + (size_t)r2 * D) + c);
            f32x4 v3 = __builtin_nontemporal_load(
                (const f32x4*)(edge_attr + (size_t)r3 * D) + c);
            f32x4 v4 = __builtin_nontemporal_load(
                (const f32x4*)(edge_attr + (size_t)r4 * D) + c);
            f32x4 v5 = __builtin_nontemporal_load(
                (const f32x4*)(edge_attr + (size_t)r5 * D) + c);
            f32x4 v6 = __builtin_nontemporal_load(
                (const f32x4*)(edge_attr + (size_t)r6 * D) + c);
            f32x4 v7 = __builtin_nontemporal_load(
                (const f32x4*)(edge_attr + (size_t)r7 * D) + c);
            acc += (v0 + v1) + (v2 + v3) + ((v4 + v5) + (v6 + v7));
        }
        if (i + 4 <= e) {
            int r0 = eid[i + 0], r1 = eid[i + 1], r2 = eid[i + 2],
                r3 = eid[i + 3];
            f32x4 v0 = __builtin_nontemporal_load(
                (const f32x4*)(edge_attr + (size_t)r0 * D) + c);
            f32x4 v1 = __builtin_nontemporal_load(
                (const f32x4*)(edge_attr + (size_t)r1 * D) + c);
            f32x4 v2 = __builtin_nontemporal_load(
                (const f32x4*)(edge_attr + (size_t)r2 * D) + c);
            f32x4 v3 = __builtin_nontemporal_load(
                (const f32x4*)(edge_attr + (size_t)r3 * D) + c);
            acc += (v0 + v1) + (v2 + v3);
            i += 4;
        }
        if (i + 2 <= e) {
            int r0 = eid[i + 0], r1 = eid[i + 1];
            f32x4 v0 = __builtin_nontemporal_load(
                (const f32x4*)(edge_attr + (size_t)r0 * D) + c);
            f32x4 v1 = __builtin_nontemporal_load(
                (const f32x4*)(edge_attr + (size_t)r1 * D) + c);
            acc += v0 + v1;
            i += 2;
        }
        if (i < e) {
            acc += __builtin_nontemporal_load(
                (const f32x4*)(edge_attr + (size_t)eid[i] * D) + c);
        }
        u32x4 p;
#pragma unroll
        for (int r = 0; r < 4; ++r) p[r] = packf(acc[r]);
        *((u32x4*)(aggp + (size_t)node * D) + c) = p;
    } else if (b < gblk + sblk) {
        int i = (b - gblk) * 256 + threadIdx.x;
        if (i < n4) {
            float4 v = ((const float4*)x)[i];
            uint4 p;
            p.x = packf(v.x);
            p.y = packf(v.y);
            p.z = packf(v.z);
            p.w = packf(v.w);
            ((uint4*)xp)[i] = p;
        }
    } else {
        int j = b - gblk - sblk;   // 0..127 output col
        int k = threadIdx.x;       // 0..255
        float w = W1[(size_t)k * D + j];
        unsigned int hi = bf16_rn(w);
        size_t o = (size_t)((k >> 3) * 128 + j) * 8 + (k & 7);
        Wh[o] = (unsigned short)hi;
        Wl[o] = (unsigned short)bf16_rn(w - bf16_f(hi));
    }
}

// ---------------------------------------------------------------------------
// In-kernel BN fold (block j < 128): scale/shift from batch stats (atomic
// reads), write frag-major split-bf16 planes + folded bias for next layer.
// ---------------------------------------------------------------------------
__device__ __forceinline__ void fold_inkernel(
    float (&sred)[2][4][128], float* gsum, float* gsq,
    const float* __restrict__ gamma, const float* __restrict__ beta,
    const float* __restrict__ W, const float* __restrict__ b,
    unsigned short* __restrict__ Wh, unsigned short* __restrict__ Wl,
    float* __restrict__ bf, float invM, int tid, int j) {
    if (tid < 128) {
        int k = tid;
        float mean = unsafeAtomicAdd(&gsum[k], 0.0f) * invM;
        float var = unsafeAtomicAdd(&gsq[k], 0.0f) * invM - mean * mean;
        float scale = gamma[k] * rsqrtf(var + 1e-5f);
        float shift = beta[k] - mean * scale;
        float wv = W[k * D + j];
        float wf = scale * wv;
        unsigned int hi = bf16_rn(wf);
        size_t o = (size_t)((k >> 3) * 128 + j) * 8 + (k & 7);
        Wh[o] = (unsigned short)hi;
        Wl[o] = (unsigned short)bf16_rn(wf - bf16_f(hi));
        float v = shift * wv;
#pragma unroll
        for (int of = 32; of; of >>= 1) v += __shfl_down(v, of);
        if ((k & 63) == 0) sred[0][0][k >> 6] = v;
    }
    __syncthreads();
    if (tid == 0) bf[j] = b[j] + sred[0][0][0] + sred[0][0][1];
}

// ---------------------------------------------------------------------------
// LDS-sourced GEMM phase: C = act(hs @ Wt^T + bias). K=128 (NS=4).
// TO_LDS: write packed result back into hs (each wave owns its 32 rows —
// reads and writes never cross waves). Else write f32 to outp (guarded).
// ---------------------------------------------------------------------------
template <bool SILU, bool STATS, bool TO_LDS>
__device__ __forceinline__ void lds_gemm_phase(
    unsigned int (&hs)[128][132], float (&sred)[2][4][128],
    const unsigned short* __restrict__ Wh,
    const unsigned short* __restrict__ Wl, const float* __restrict__ bias,
    float* gsum, float* gsq, float* __restrict__ outp, int tid, int w, int lr,
    int lk, int row0g, int M) {
    facc acc[2][8];
#pragma unroll
    for (int rt = 0; rt < 2; ++rt)
#pragma unroll
        for (int ct = 0; ct < 8; ++ct)
#pragma unroll
            for (int r = 0; r < 4; ++r) acc[rt][ct][r] = 0.f;

    for (int s = 0; s < 4; ++s) {
        const int kb = s * 32 + lk * 8;
        bfrag ah[2], al[2];
#pragma unroll
        for (int rt = 0; rt < 2; ++rt) {
            const int lrow = w * 32 + rt * 16 + lr;
            const u32x4* p = (const u32x4*)&hs[lrow][kb];
            u32x4 q0 = p[0], q1 = p[1];
            unsigned int ua[8] = {q0.x, q0.y, q0.z, q0.w,
                                  q1.x, q1.y, q1.z, q1.w};
            splitA(ua, ah[rt], al[rt]);
        }
        bfrag bh[8], bl[8];
        const int fb = (s * 4 + lk) * 128;
#pragma unroll
        for (int ct = 0; ct < 8; ++ct) {
            size_t o = (size_t)(fb + ct * 16 + lr) * 8;
            bh[ct] = *(const bfrag*)(Wh + o);
            bl[ct] = *(const bfrag*)(Wl + o);
        }
#pragma unroll
        for (int rt = 0; rt < 2; ++rt)
#pragma unroll
            for (int ct = 0; ct < 8; ++ct)
                acc[rt][ct] = mfma16(ah[rt], bh[ct], acc[rt][ct]);
#pragma unroll
        for (int rt = 0; rt < 2; ++rt)
#pragma unroll
            for (int ct = 0; ct < 8; ++ct)
                acc[rt][ct] = mfma16(ah[rt], bl[ct], acc[rt][ct]);
#pragma unroll
        for (int rt = 0; rt < 2; ++rt)
#pragma unroll
            for (int ct = 0; ct < 8; ++ct)
                acc[rt][ct] = mfma16(al[rt], bh[ct], acc[rt][ct]);
    }

#pragma unroll
    for (int ct = 0; ct < 8; ++ct) {
        const int col = ct * 16 + lr;
        const float bj = bias[col];
        float s_ = 0.f, q_ = 0.f;
#pragma unroll
        for (int rt = 0; rt < 2; ++rt) {
            const int lbase = w * 32 + rt * 16 + lk * 4;
#pragma unroll
            for (int r = 0; r < 4; ++r) {
                float v = acc[rt][ct][r] + bj;
                if (SILU) v = v / (1.0f + __expf(-v));
                int crow = row0g + lbase + r;
                if (TO_LDS) {
                    hs[lbase + r][col] = packf(v);
                } else {
                    if (crow < M) outp[(size_t)crow * D + col] = v;
                }
                if (STATS && crow < M) {
                    s_ += v;
                    q_ += v * v;
                }
            }
        }
        if (STATS) {
            s_ += __shfl_xor(s_, 16);
            s_ += __shfl_xor(s_, 32);
            q_ += __shfl_xor(q_, 16);
            q_ += __shfl_xor(q_, 32);
            if (lk == 0) {
                sred[0][w][col] = s_;
                sred[1][w][col] = q_;
            }
        }
    }
    if (STATS) {
        __syncthreads();
        if (tid < 128) {
            float v = sred[0][0][tid] + sred[0][1][tid] + sred[0][2][tid] +
                      sred[0][3][tid];
            unsafeAtomicAdd(&gsum[tid], v);
        } else {
            int c = tid - 128;
            float v = sred[1][0][c] + sred[1][1][c] + sred[1][2][c] +
                      sred[1][3][c];
            unsafeAtomicAdd(&gsq[c], v);
        }
    }
}

// ---------------------------------------------------------------------------
// Persistent fused MLP: GEMM1(global->LDS) -> grid-arrive -> fold W2 (blocks
// 0..127) -> GEMM2(LDS->LDS) -> fold W3 -> GEMM3(LDS->out). Each block owns
// the same 128 rows through all layers; h1/h2 never touch HBM. 391 blocks
// co-resident at __launch_bounds__(256,2) (LDS 71.7KB <= 80KB/block).
// ---------------------------------------------------------------------------
__global__ __launch_bounds__(256, 2) void mlp_fused(
    const unsigned int* __restrict__ xp, const unsigned int* __restrict__ aggp,
    const unsigned short* __restrict__ W1h,
    const unsigned short* __restrict__ W1l, const float* __restrict__ b1,
    const float* __restrict__ g1, const float* __restrict__ be1,
    const float* __restrict__ W2, const float* __restrict__ b2,
    const float* __restrict__ g2, const float* __restrict__ be2,
    const float* __restrict__ W3, const float* __restrict__ b3,
    unsigned short* __restrict__ W2h, unsigned short* __restrict__ W2l,
    float* __restrict__ b2f, unsigned short* __restrict__ W3h,
    unsigned short* __restrict__ W3l, float* __restrict__ b3f,
    float* sum1, float* sq1, float* sum2, float* sq2, int* ctrs,
    float* __restrict__ out, int M, float invM) {
    __shared__ unsigned int hs[128][132];   // padded: 528B row stride
    __shared__ float sred[2][4][128];
    const int tid = threadIdx.x;
    const int w = tid >> 6;
    const int l = tid & 63;
    const int lr = l & 15;
    const int lk = l >> 4;
    const int row0g = blockIdx.x * 128;
    const int nblk = (int)gridDim.x;

    // ---------- phase 1: h1 = SiLU([x|agg] @ W1^T + b1) -> LDS ----------
    {
        facc acc[2][8];
#pragma unroll
        for (int rt = 0; rt < 2; ++rt)
#pragma unroll
            for (int ct = 0; ct < 8; ++ct)
#pragma unroll
                for (int r = 0; r < 4; ++r) acc[rt][ct][r] = 0.f;

        for (int s = 0; s < 8; ++s) {
            const int kb = s * 32 + lk * 8;
            bfrag ah[2], al[2];
#pragma unroll
            for (int rt = 0; rt < 2; ++rt) {
                const int arow = row0g + w * 32 + rt * 16 + lr;
                const unsigned int* As = (s < 4) ? xp : aggp;
                const int kk = (s < 4) ? kb : kb - 128;
                u32x4 q0 = {0u, 0u, 0u, 0u}, q1 = {0u, 0u, 0u, 0u};
                if (arow < M) {
                    const u32x4* p =
                        (const u32x4*)(As + (size_t)arow * D + kk);
                    q0 = p[0];
                    q1 = p[1];
                }
                unsigned int ua[8] = {q0.x, q0.y, q0.z, q0.w,
                                      q1.x, q1.y, q1.z, q1.w};
                splitA(ua, ah[rt], al[rt]);
            }
            bfrag bh[8], bl[8];
            const int fb = (s * 4 + lk) * 128;
#pragma unroll
            for (int ct = 0; ct < 8; ++ct) {
                size_t o = (size_t)(fb + ct * 16 + lr) * 8;
                bh[ct] = *(const bfrag*)(W1h + o);
                bl[ct] = *(const bfrag*)(W1l + o);
            }
#pragma unroll
            for (int rt = 0; rt < 2; ++rt)
#pragma unroll
                for (int ct = 0; ct < 8; ++ct)
                    acc[rt][ct] = mfma16(ah[rt], bh[ct], acc[rt][ct]);
#pragma unroll
            for (int rt = 0; rt < 2; ++rt)
#pragma unroll
                for (int ct = 0; ct < 8; ++ct)
                    acc[rt][ct] = mfma16(ah[rt], bl[ct], acc[rt][ct]);
#pragma unroll
            for (int rt = 0; rt < 2; ++rt)
#pragma unroll
                for (int ct = 0; ct < 8; ++ct)
                    acc[rt][ct] = mfma16(al[rt], bh[ct], acc[rt][ct]);
        }
#pragma unroll
        for (int ct = 0; ct < 8; ++ct) {
            const int col = ct * 16 + lr;
            const float bj = b1[col];
            float s_ = 0.f, q_ = 0.f;
#pragma unroll
            for (int rt = 0; rt < 2; ++rt) {
                const int lbase = w * 32 + rt * 16 + lk * 4;
#pragma unroll
                for (int r = 0; r < 4; ++r) {
                    float v = acc[rt][ct][r] + bj;
                    v = v / (1.0f + __expf(-v));
                    hs[lbase + r][col] = packf(v);
                    if (row0g + lbase + r < M) {
                        s_ += v;
                        q_ += v * v;
                    }
                }
            }
            s_ += __shfl_xor(s_, 16);
            s_ += __shfl_xor(s_, 32);
            q_ += __shfl_xor(q_, 16);
            q_ += __shfl_xor(q_, 32);
            if (lk == 0) {
                sred[0][w][col] = s_;
                sred[1][w][col] = q_;
            }
        }
        __syncthreads();
        if (tid < 128) {
            float v = sred[0][0][tid] + sred[0][1][tid] + sred[0][2][tid] +
                      sred[0][3][tid];
            unsafeAtomicAdd(&sum1[tid], v);
        } else {
            int c = tid - 128;
            float v = sred[1][0][c] + sred[1][1][c] + sred[1][2][c] +
                      sred[1][3][c];
            unsafeAtomicAdd(&sq1[c], v);
        }
    }
    __threadfence();
    __syncthreads();
    if (tid == 0) atomicAdd(&ctrs[0], 1);

    // ---------- fold W2 (blocks 0..127) ----------
    if (blockIdx.x < 128) {
        if (tid == 0)
            while (atomicAdd(&ctrs[0], 0) < nblk) __builtin_amdgcn_s_sleep(8);
        __syncthreads();
        __threadfence();
        fold_inkernel(sred, sum1, sq1, g1, be1, W2, b2, W2h, W2l, b2f, invM,
                      tid, blockIdx.x);
        if (tid == 0) {
            __threadfence();
            atomicAdd(&ctrs[1], 1);
        }
    }
    if (tid == 0)
        while (atomicAdd(&ctrs[1], 0) < 128) __builtin_amdgcn_s_sleep(8);
    __syncthreads();
    __threadfence();

    // ---------- phase 2: h2 = SiLU(h1 @ W2f^T + b2f) -> LDS ----------
    lds_gemm_phase<true, true, true>(hs, sred, W2h, W2l, b2f, sum2, sq2,
                                     nullptr, tid, w, lr, lk, row0g, M);
    __threadfence();
    __syncthreads();
    if (tid == 0) atomicAdd(&ctrs[2], 1);

    // ---------- fold W3 (blocks 0..127) ----------
    if (blockIdx.x < 128) {
        if (tid == 0)
            while (atomicAdd(&ctrs[2], 0) < nblk) __builtin_amdgcn_s_sleep(8);
        __syncthreads();
        __threadfence();
        fold_inkernel(sred, sum2, sq2, g2, be2, W3, b3, W3h, W3l, b3f, invM,
                      tid, blockIdx.x);
        if (tid == 0) {
            __threadfence();
            atomicAdd(&ctrs[3], 1);
        }
    }
    if (tid == 0)
        while (atomicAdd(&ctrs[3], 0) < 128) __builtin_amdgcn_s_sleep(8);
    __syncthreads();
    __threadfence();

    // ---------- phase 3: out = h2 @ W3f^T + b3f ----------
    lds_gemm_phase<false, false, false>(hs, sred, W3h, W3l, b3f, nullptr,
                                        nullptr, out, tid, w, lr, lk, row0g,
                                        M);
}

extern "C" void kernel_launch(void* const* d_in, const int* in_sizes, int n_in,
                              void* d_out, int out_size, void* d_ws,
                              size_t ws_size, hipStream_t stream) {
    const float* x     = (const float*)d_in[0];
    const int*   eidx  = (const int*)d_in[1];
    const float* eattr = (const float*)d_in[2];
    const float* W1  = (const float*)d_in[3];
    const float* b1  = (const float*)d_in[4];
    const float* g1  = (const float*)d_in[5];
    const float* be1 = (const float*)d_in[6];
    const float* W2  = (const float*)d_in[7];
    const float* b2  = (const float*)d_in[8];
    const float* g2  = (const float*)d_in[9];
    const float* be2 = (const float*)d_in[10];
    const float* W3  = (const float*)d_in[11];
    const float* b3  = (const float*)d_in[12];

    const int M = in_sizes[0] / D;   // 50000
    const int E = in_sizes[1] / 2;   // 600000
    const int* srcIdx = eidx;

    unsigned int* wsu = (unsigned int*)d_ws;
    unsigned int* aggp = wsu;                       // M*D packed
    unsigned int* xp   = aggp + (size_t)M * D;      // M*D
    // zeroed region: counts[M], ctrs[8], stats[4*D] -> single memset
    int* counts = (int*)(xp + (size_t)M * D);       // M
    int* ctrs   = counts + M;                       // 8
    float* sum1 = (float*)(ctrs + 8);               // D
    float* sq1  = sum1 + D;
    float* sum2 = sq1 + D;
    float* sq2  = sum2 + D;
    float* b2f  = sq2 + D;
    float* b3f  = b2f + D;
    int* off    = (int*)(b3f + D);                  // M+4
    int* cur    = off + M + 4;                      // M
    int* eid    = cur + M;                          // E
    int* bsum   = eid + E;                          // 64
    unsigned short* W1h = (unsigned short*)(bsum + 64);  // 128*256
    unsigned short* W1l = W1h + 256 * D;
    unsigned short* W2h = W1l + 256 * D;                 // 128*128
    unsigned short* W2l = W2h + D * D;
    unsigned short* W3h = W2l + D * D;
    unsigned short* W3l = W3h + D * D;

    float* out = (float*)d_out;

    (void)hipMemsetAsync(counts, 0, ((size_t)M + 8 + 4 * D) * sizeof(int),
                         stream);

    const int eblk = (E + 255) / 256;
    hist_kernel<<<eblk, 256, 0, stream>>>(srcIdx, counts, E);

    const int nbk = (M + SCHUNK - 1) / SCHUNK;   // 25 (co-resident)
    scanF_kernel<<<nbk, 256, 0, stream>>>(counts, bsum, &ctrs[4], off, cur, M,
                                          nbk);
    fill_kernel<<<eblk, 256, 0, stream>>>(srcIdx, cur, eid, E);

    const int gblk = (M + 7) / 8;
    const int sblk = (M * 32 + 255) / 256;
    gather_split_kernel<<<gblk + sblk + 128, 256, 0, stream>>>(
        eattr, eid, off, aggp, M, x, xp, M * 32, W1, W1h, W1l, gblk, sblk);

    const int nblk = (M + 127) / 128;   // 391 <= 512 co-resident
    mlp_fused<<<nblk, 256, 0, stream>>>(
        xp, aggp, W1h, W1l, b1, g1, be1, W2, b2, g2, be2, W3, b3, W2h, W2l,
        b2f, W3h, W3l, b3f, sum1, sq1, sum2, sq2, ctrs, out, M,
        1.0f / (float)M);
}

// Round 15
// 282.117 us; speedup vs baseline: 1.2999x; 1.2999x over previous
//
#include <hip/hip_runtime.h>
#include <hip/hip_bf16.h>

#define D 128

typedef __attribute__((ext_vector_type(8))) short bfrag;   // 8 bf16 (4 VGPRs)
typedef __attribute__((ext_vector_type(4))) float facc;    // 4 f32 acc
typedef __attribute__((ext_vector_type(4))) unsigned int u32x4;
typedef __attribute__((ext_vector_type(4))) float f32x4;

__device__ __forceinline__ facc mfma16(bfrag a, bfrag b, facc c) {
    return __builtin_amdgcn_mfma_f32_16x16x32_bf16(a, b, c, 0, 0, 0);
}
__device__ __forceinline__ unsigned int bf16_rn(float f) {
    unsigned int u = __float_as_uint(f);
    u += 0x7FFF + ((u >> 16) & 1);   // round-nearest-even
    return u >> 16;
}
__device__ __forceinline__ float bf16_f(unsigned int h) {
    return __uint_as_float(h << 16);
}
// pack f32 -> (bf16_hi << 16) | bf16_lo
__device__ __forceinline__ unsigned int packf(float v) {
    unsigned int hi = bf16_rn(v);
    unsigned int lo = bf16_rn(v - bf16_f(hi));
    return (hi << 16) | lo;
}

// ---------------------------------------------------------------------------
// Histogram of edge source nodes.
// ---------------------------------------------------------------------------
__global__ __launch_bounds__(256) void hist_kernel(
    const int* __restrict__ src, int* __restrict__ counts, int nedges) {
    int e = blockIdx.x * 256 + threadIdx.x;
    if (e < nedges) atomicAdd(&counts[src[e]], 1);
}

// ---------------------------------------------------------------------------
// Single-dispatch exclusive scan of counts[n] -> off[n+1], cur[n].
// 25 co-resident blocks; device-scope arrival counter + spin.
// ---------------------------------------------------------------------------
#define SCHUNK 2048
__global__ __launch_bounds__(256) void scanF_kernel(
    const int* __restrict__ counts, int* __restrict__ bsum,
    int* __restrict__ ctr, int* __restrict__ off, int* __restrict__ cur,
    int n, int nbk) {
    __shared__ int sd[256];
    __shared__ int sbase;
    const int tid = threadIdx.x;
    const int b = blockIdx.x;
    const int base = b * SCHUNK + tid * 8;
    int loc[8];
    int s = 0;
#pragma unroll
    for (int j = 0; j < 8; ++j) {
        int idx = base + j;
        int c = (idx < n) ? counts[idx] : 0;
        loc[j] = c;
        s += c;
    }
    sd[tid] = s;
    __syncthreads();
#pragma unroll
    for (int d2 = 1; d2 < 256; d2 <<= 1) {
        int t = (tid >= d2) ? sd[tid - d2] : 0;
        __syncthreads();
        sd[tid] += t;
        __syncthreads();
    }
    if (tid == 0) {
        atomicExch(&bsum[b], sd[255]);
        __threadfence();
        atomicAdd(ctr, 1);
        while (atomicAdd(ctr, 0) < nbk) __builtin_amdgcn_s_sleep(8);
    }
    __syncthreads();
    if (tid < 64) {
        int t = (tid < b) ? atomicAdd(&bsum[tid], 0) : 0;
#pragma unroll
        for (int o = 32; o; o >>= 1) t += __shfl_down(t, o);
        if (tid == 0) sbase = t;
    }
    __syncthreads();
    int pre = sbase + sd[tid] - s;
#pragma unroll
    for (int j = 0; j < 8; ++j) {
        int idx = base + j;
        if (idx < n) {
            off[idx] = pre;
            cur[idx] = pre;
            pre += loc[j];
        }
    }
    if (b == nbk - 1 && tid == 0) off[n] = sbase + sd[255];
}

// ---------------------------------------------------------------------------
// CSR fill: bin edge ids by source node.
// ---------------------------------------------------------------------------
__global__ void fill_kernel(const int* __restrict__ src, int* __restrict__ cur,
                            int* __restrict__ eid, int nedges) {
    int e = blockIdx.x * 256 + threadIdx.x;
    if (e < nedges) {
        int slot = atomicAdd(&cur[src[e]], 1);
        eid[slot] = e;
    }
}

// ---------------------------------------------------------------------------
// Fused gather + x-split + W1-prep (R13 structure, unchanged).
// Gather: one half-wave (32 lanes x 16B = 512B) per node, 8-deep batches.
// ---------------------------------------------------------------------------
__global__ __launch_bounds__(256) void gather_split_kernel(
    const float* __restrict__ edge_attr, const int* __restrict__ eid,
    const int* __restrict__ off, unsigned int* __restrict__ aggp, int nnodes,
    const float* __restrict__ x, unsigned int* __restrict__ xp, int n4,
    const float* __restrict__ W1, unsigned short* __restrict__ Wh,
    unsigned short* __restrict__ Wl, int gblk, int sblk) {
    const int b = blockIdx.x;
    if (b < gblk) {
        int node = b * 8 + (threadIdx.x >> 5);   // half-wave per node
        if (node >= nnodes) return;
        const int c = threadIdx.x & 31;
        int i = off[node];
        const int e = off[node + 1];
        f32x4 acc = {0.f, 0.f, 0.f, 0.f};

        for (; i + 8 <= e; i += 8) {
            int r0 = eid[i + 0], r1 = eid[i + 1], r2 = eid[i + 2],
                r3 = eid[i + 3], r4 = eid[i + 4], r5 = eid[i + 5],
                r6 = eid[i + 6], r7 = eid[i + 7];
            f32x4 v0 = __builtin_nontemporal_load(
                (const f32x4*)(edge_attr + (size_t)r0 * D) + c);
            f32x4 v1 = __builtin_nontemporal_load(
                (const f32x4*)(edge_attr + (size_t)r1 * D) + c);
            f32x4 v2 = __builtin_nontemporal_load(
                (const f32x4*)(edge_attr + (size_t)r2 * D) + c);
            f32x4 v3 = __builtin_nontemporal_load(
                (const f32x4*)(edge_attr + (size_t)r3 * D) + c);
            f32x4 v4 = __builtin_nontemporal_load(
                (const f32x4*)(edge_attr + (size_t)r4 * D) + c);
            f32x4 v5 = __builtin_nontemporal_load(
                (const f32x4*)(edge_attr + (size_t)r5 * D) + c);
            f32x4 v6 = __builtin_nontemporal_load(
                (const f32x4*)(edge_attr + (size_t)r6 * D) + c);
            f32x4 v7 = __builtin_nontemporal_load(
                (const f32x4*)(edge_attr + (size_t)r7 * D) + c);
            acc += (v0 + v1) + (v2 + v3) + ((v4 + v5) + (v6 + v7));
        }
        if (i + 4 <= e) {
            int r0 = eid[i + 0], r1 = eid[i + 1], r2 = eid[i + 2],
                r3 = eid[i + 3];
            f32x4 v0 = __builtin_nontemporal_load(
                (const f32x4*)(edge_attr + (size_t)r0 * D) + c);
            f32x4 v1 = __builtin_nontemporal_load(
                (const f32x4*)(edge_attr + (size_t)r1 * D) + c);
            f32x4 v2 = __builtin_nontemporal_load(
                (const f32x4*)(edge_attr + (size_t)r2 * D) + c);
            f32x4 v3 = __builtin_nontemporal_load(
                (const f32x4*)(edge_attr + (size_t)r3 * D) + c);
            acc += (v0 + v1) + (v2 + v3);
            i += 4;
        }
        if (i + 2 <= e) {
            int r0 = eid[i + 0], r1 = eid[i + 1];
            f32x4 v0 = __builtin_nontemporal_load(
                (const f32x4*)(edge_attr + (size_t)r0 * D) + c);
            f32x4 v1 = __builtin_nontemporal_load(
                (const f32x4*)(edge_attr + (size_t)r1 * D) + c);
            acc += v0 + v1;
            i += 2;
        }
        if (i < e) {
            acc += __builtin_nontemporal_load(
                (const f32x4*)(edge_attr + (size_t)eid[i] * D) + c);
        }
        u32x4 p;
#pragma unroll
        for (int r = 0; r < 4; ++r) p[r] = packf(acc[r]);
        *((u32x4*)(aggp + (size_t)node * D) + c) = p;
    } else if (b < gblk + sblk) {
        int i = (b - gblk) * 256 + threadIdx.x;
        if (i < n4) {
            float4 v = ((const float4*)x)[i];
            uint4 p;
            p.x = packf(v.x);
            p.y = packf(v.y);
            p.z = packf(v.z);
            p.w = packf(v.w);
            ((uint4*)xp)[i] = p;
        }
    } else {
        int j = b - gblk - sblk;   // 0..127 output col
        int k = threadIdx.x;       // 0..255
        float w = W1[(size_t)k * D + j];
        unsigned int hi = bf16_rn(w);
        size_t o = (size_t)((k >> 3) * 128 + j) * 8 + (k & 7);
        Wh[o] = (unsigned short)hi;
        Wl[o] = (unsigned short)bf16_rn(w - bf16_f(hi));
    }
}

// ---------------------------------------------------------------------------
// Split-bf16 MFMA GEMM, pre-split packed A (uint = hi|lo), frag-major W.
// 3 MFMAs per tile: Ah*Wh + Ah*Wl + Al*Wh. Block = 4 waves, BM = 128.
// K==256: k<128 from A0, k>=128 from A1 (implicit concat).
// FOLD: the LAST-ARRIVING block (atomic counter, no spin) folds BN batch
// stats into the next layer's weights (frag-major split planes + bias) —
// replaces a separate fold dispatch. Deterministic: fold math is
// independent of which block runs it; stats read via device-scope atomics.
// C/D layout (m89): col = lane&15, row = (lane>>4)*4 + reg.
// ---------------------------------------------------------------------------
template <int K, bool SILU, bool STATS, bool PACKOUT, bool FOLD>
__global__ __launch_bounds__(256, 2) void gemm_mfma(
    const unsigned int* __restrict__ A0, const unsigned int* __restrict__ A1,
    const unsigned short* __restrict__ Wh,
    const unsigned short* __restrict__ Wl,
    const float* __restrict__ bias, unsigned int* __restrict__ Cp,
    float* __restrict__ Cf, float* __restrict__ gsum, float* __restrict__ gsq,
    int M,
    // FOLD args (next layer):
    const float* __restrict__ gamma, const float* __restrict__ beta,
    const float* __restrict__ Wn, const float* __restrict__ bn,
    unsigned short* __restrict__ Whn, unsigned short* __restrict__ Wln,
    float* __restrict__ bfn, float invM, int* ctr) {
    constexpr int NS = K / 32;
    const int tid = threadIdx.x;
    const int w = tid >> 6;
    const int l = tid & 63;
    const int lr = l & 15;
    const int lk = l >> 4;
    const int row0 = blockIdx.x * 128 + w * 32;

    facc acc[2][8];
#pragma unroll
    for (int rt = 0; rt < 2; ++rt)
#pragma unroll
        for (int ct = 0; ct < 8; ++ct)
#pragma unroll
            for (int r = 0; r < 4; ++r) acc[rt][ct][r] = 0.f;

    for (int s = 0; s < NS; ++s) {
        const int kb = s * 32 + lk * 8;
        bfrag ah[2], al[2];
#pragma unroll
        for (int rt = 0; rt < 2; ++rt) {
            const int arow = row0 + rt * 16 + lr;
            const unsigned int* As = A0;
            int kk = kb;
            if (K == 256 && s >= 4) { As = A1; kk = kb - 128; }
            u32x4 q0 = {0u, 0u, 0u, 0u}, q1 = {0u, 0u, 0u, 0u};
            if (arow < M) {
                const u32x4* p = (const u32x4*)(As + (size_t)arow * D + kk);
                q0 = p[0];
                q1 = p[1];
            }
            unsigned int ua[8] = {q0.x, q0.y, q0.z, q0.w,
                                  q1.x, q1.y, q1.z, q1.w};
            u32x4 uh, ul;
#pragma unroll
            for (int r = 0; r < 4; ++r) {
                uh[r] = __builtin_amdgcn_perm(ua[2 * r + 1], ua[2 * r],
                                              0x07060302u);
                ul[r] = __builtin_amdgcn_perm(ua[2 * r + 1], ua[2 * r],
                                              0x05040100u);
            }
            ah[rt] = __builtin_bit_cast(bfrag, uh);
            al[rt] = __builtin_bit_cast(bfrag, ul);
        }
        bfrag bh[8], bl[8];
        const int fb = (s * 4 + lk) * 128;
#pragma unroll
        for (int ct = 0; ct < 8; ++ct) {
            size_t o = (size_t)(fb + ct * 16 + lr) * 8;
            bh[ct] = *(const bfrag*)(Wh + o);
            bl[ct] = *(const bfrag*)(Wl + o);
        }
#pragma unroll
        for (int rt = 0; rt < 2; ++rt)
#pragma unroll
            for (int ct = 0; ct < 8; ++ct)
                acc[rt][ct] = mfma16(ah[rt], bh[ct], acc[rt][ct]);
#pragma unroll
        for (int rt = 0; rt < 2; ++rt)
#pragma unroll
            for (int ct = 0; ct < 8; ++ct)
                acc[rt][ct] = mfma16(ah[rt], bl[ct], acc[rt][ct]);
#pragma unroll
        for (int rt = 0; rt < 2; ++rt)
#pragma unroll
            for (int ct = 0; ct < 8; ++ct)
                acc[rt][ct] = mfma16(al[rt], bh[ct], acc[rt][ct]);
    }

    __shared__ float sred[2][4][128];
#pragma unroll
    for (int ct = 0; ct < 8; ++ct) {
        const int col = ct * 16 + lr;
        const float bj = bias[col];
        float s = 0.f, q = 0.f;
#pragma unroll
        for (int rt = 0; rt < 2; ++rt) {
            const int base = row0 + rt * 16 + lk * 4;
#pragma unroll
            for (int r = 0; r < 4; ++r) {
                int crow = base + r;
                if (crow < M) {
                    float v = acc[rt][ct][r] + bj;
                    if (SILU) v = v / (1.0f + __expf(-v));
                    if (PACKOUT) Cp[(size_t)crow * D + col] = packf(v);
                    else         Cf[(size_t)crow * D + col] = v;
                    if (STATS) { s += v; q += v * v; }
                }
            }
        }
        if (STATS) {
            s += __shfl_xor(s, 16);
            s += __shfl_xor(s, 32);
            q += __shfl_xor(q, 16);
            q += __shfl_xor(q, 32);
            if (lk == 0) {
                sred[0][w][col] = s;
                sred[1][w][col] = q;
            }
        }
    }
    if (STATS) {
        __syncthreads();
        if (tid < 128) {
            float v = sred[0][0][tid] + sred[0][1][tid] + sred[0][2][tid] +
                      sred[0][3][tid];
            unsafeAtomicAdd(&gsum[tid], v);
        } else {
            int c = tid - 128;
            float v = sred[1][0][c] + sred[1][1][c] + sred[1][2][c] +
                      sred[1][3][c];
            unsafeAtomicAdd(&gsq[c], v);
        }
    }
    if (FOLD) {
        __shared__ int slast;
        if (tid == 0) {
            __threadfence();
            int old = atomicAdd(ctr, 1);
            slast = (old == (int)gridDim.x - 1) ? 1 : 0;
        }
        __syncthreads();
        if (slast) {
            // scale/shift per k into LDS (reuse sred)
            float* sscale = &sred[0][0][0];
            float* sshift = &sred[0][1][0];
            float* bhalf = &sred[1][0][0];   // 256 floats
            if (tid < 128) {
                float mean = unsafeAtomicAdd(&gsum[tid], 0.0f) * invM;
                float var =
                    unsafeAtomicAdd(&gsq[tid], 0.0f) * invM - mean * mean;
                float sc = gamma[tid] * rsqrtf(var + 1e-5f);
                sscale[tid] = sc;
                sshift[tid] = beta[tid] - mean * sc;
            }
            __syncthreads();
            const int j = tid & 127;
            const int k0 = (tid >> 7) * 64;
            float bacc = 0.f;
            for (int k = k0; k < k0 + 64; ++k) {
                float wv = Wn[k * D + j];
                float wf = sscale[k] * wv;
                unsigned int hi = bf16_rn(wf);
                size_t o = (size_t)((k >> 3) * 128 + j) * 8 + (k & 7);
                Whn[o] = (unsigned short)hi;
                Wln[o] = (unsigned short)bf16_rn(wf - bf16_f(hi));
                bacc += sshift[k] * wv;
            }
            bhalf[tid] = bacc;
            __syncthreads();
            if (tid < 128) bfn[tid] = bn[tid] + bhalf[tid] + bhalf[tid + 128];
        }
    }
}

extern "C" void kernel_launch(void* const* d_in, const int* in_sizes, int n_in,
                              void* d_out, int out_size, void* d_ws,
                              size_t ws_size, hipStream_t stream) {
    const float* x     = (const float*)d_in[0];
    const int*   eidx  = (const int*)d_in[1];
    const float* eattr = (const float*)d_in[2];
    const float* W1  = (const float*)d_in[3];
    const float* b1  = (const float*)d_in[4];
    const float* g1  = (const float*)d_in[5];
    const float* be1 = (const float*)d_in[6];
    const float* W2  = (const float*)d_in[7];
    const float* b2  = (const float*)d_in[8];
    const float* g2  = (const float*)d_in[9];
    const float* be2 = (const float*)d_in[10];
    const float* W3  = (const float*)d_in[11];
    const float* b3  = (const float*)d_in[12];

    const int M = in_sizes[0] / D;   // 50000
    const int E = in_sizes[1] / 2;   // 600000
    const int* srcIdx = eidx;

    unsigned int* wsu = (unsigned int*)d_ws;
    unsigned int* aggp = wsu;                       // M*D packed
    unsigned int* xp   = aggp + (size_t)M * D;      // M*D
    unsigned int* h1p  = xp + (size_t)M * D;        // M*D
    unsigned int* h2p  = h1p + (size_t)M * D;       // M*D
    // zeroed region: counts[M], ctrs[8], stats[4*D] -> single memset
    int* counts = (int*)(h2p + (size_t)M * D);      // M
    int* ctrs   = counts + M;                       // 8
    float* sum1 = (float*)(ctrs + 8);               // D
    float* sq1  = sum1 + D;
    float* sum2 = sq1 + D;
    float* sq2  = sum2 + D;
    float* b2f  = sq2 + D;
    float* b3f  = b2f + D;
    int* off    = (int*)(b3f + D);                  // M+4
    int* cur    = off + M + 4;                      // M
    int* eid    = cur + M;                          // E
    int* bsum   = eid + E;                          // 64
    unsigned short* W1h = (unsigned short*)(bsum + 64);  // 128*256
    unsigned short* W1l = W1h + 256 * D;
    unsigned short* W2h = W1l + 256 * D;                 // 128*128
    unsigned short* W2l = W2h + D * D;
    unsigned short* W3h = W2l + D * D;
    unsigned short* W3l = W3h + D * D;

    float* out = (float*)d_out;
    const float invM = 1.0f / (float)M;

    (void)hipMemsetAsync(counts, 0, ((size_t)M + 8 + 4 * D) * sizeof(int),
                         stream);

    const int eblk = (E + 255) / 256;
    hist_kernel<<<eblk, 256, 0, stream>>>(srcIdx, counts, E);

    const int nbk = (M + SCHUNK - 1) / SCHUNK;   // 25 (co-resident)
    scanF_kernel<<<nbk, 256, 0, stream>>>(counts, bsum, &ctrs[0], off, cur, M,
                                          nbk);
    fill_kernel<<<eblk, 256, 0, stream>>>(srcIdx, cur, eid, E);

    const int gblk = (M + 7) / 8;
    const int sblk = (M * 32 + 255) / 256;
    gather_split_kernel<<<gblk + sblk + 128, 256, 0, stream>>>(
        eattr, eid, off, aggp, M, x, xp, M * 32, W1, W1h, W1l, gblk, sblk);

    const int nblk = (M + 127) / 128;
    // gemm1 + fold(BN1 -> W2f) in last block's epilogue
    gemm_mfma<256, true, true, true, true><<<nblk, 256, 0, stream>>>(
        xp, aggp, W1h, W1l, b1, h1p, nullptr, sum1, sq1, M,
        g1, be1, W2, b2, W2h, W2l, b2f, invM, &ctrs[1]);
    // gemm2 + fold(BN2 -> W3f)
    gemm_mfma<128, true, true, true, true><<<nblk, 256, 0, stream>>>(
        h1p, nullptr, W2h, W2l, b2f, h2p, nullptr, sum2, sq2, M,
        g2, be2, W3, b3, W3h, W3l, b3f, invM, &ctrs[2]);
    // gemm3 (no stats, no fold)
    gemm_mfma<128, false, false, false, false><<<nblk, 256, 0, stream>>>(
        h2p, nullptr, W3h, W3l, b3f, nullptr, out, nullptr, nullptr, M,
        nullptr, nullptr, nullptr, nullptr, nullptr, nullptr, nullptr, 0.f,
        nullptr);
}

// Round 16
// 238.719 us; speedup vs baseline: 1.5362x; 1.1818x over previous
//
#include <hip/hip_runtime.h>
#include <hip/hip_bf16.h>

#define D 128

typedef __attribute__((ext_vector_type(8))) short bfrag;   // 8 bf16 (4 VGPRs)
typedef __attribute__((ext_vector_type(4))) float facc;    // 4 f32 acc
typedef __attribute__((ext_vector_type(4))) unsigned int u32x4;
typedef __attribute__((ext_vector_type(4))) float f32x4;

__device__ __forceinline__ facc mfma16(bfrag a, bfrag b, facc c) {
    return __builtin_amdgcn_mfma_f32_16x16x32_bf16(a, b, c, 0, 0, 0);
}
__device__ __forceinline__ unsigned int bf16_rn(float f) {
    unsigned int u = __float_as_uint(f);
    u += 0x7FFF + ((u >> 16) & 1);   // round-nearest-even
    return u >> 16;
}
__device__ __forceinline__ float bf16_f(unsigned int h) {
    return __uint_as_float(h << 16);
}
// pack f32 -> (bf16_hi << 16) | bf16_lo
__device__ __forceinline__ unsigned int packf(float v) {
    unsigned int hi = bf16_rn(v);
    unsigned int lo = bf16_rn(v - bf16_f(hi));
    return (hi << 16) | lo;
}

// ---------------------------------------------------------------------------
// Histogram of edge source nodes.
// ---------------------------------------------------------------------------
__global__ __launch_bounds__(256) void hist_kernel(
    const int* __restrict__ src, int* __restrict__ counts, int nedges) {
    int e = blockIdx.x * 256 + threadIdx.x;
    if (e < nedges) atomicAdd(&counts[src[e]], 1);
}

// ---------------------------------------------------------------------------
// Single-dispatch exclusive scan of counts[n] -> off[n+1], cur[n].
// 25 co-resident blocks; device-scope arrival counter + spin.
// ---------------------------------------------------------------------------
#define SCHUNK 2048
__global__ __launch_bounds__(256) void scanF_kernel(
    const int* __restrict__ counts, int* __restrict__ bsum,
    int* __restrict__ ctr, int* __restrict__ off, int* __restrict__ cur,
    int n, int nbk) {
    __shared__ int sd[256];
    __shared__ int sbase;
    const int tid = threadIdx.x;
    const int b = blockIdx.x;
    const int base = b * SCHUNK + tid * 8;
    int loc[8];
    int s = 0;
#pragma unroll
    for (int j = 0; j < 8; ++j) {
        int idx = base + j;
        int c = (idx < n) ? counts[idx] : 0;
        loc[j] = c;
        s += c;
    }
    sd[tid] = s;
    __syncthreads();
#pragma unroll
    for (int d2 = 1; d2 < 256; d2 <<= 1) {
        int t = (tid >= d2) ? sd[tid - d2] : 0;
        __syncthreads();
        sd[tid] += t;
        __syncthreads();
    }
    if (tid == 0) {
        atomicExch(&bsum[b], sd[255]);
        __threadfence();
        atomicAdd(ctr, 1);
        while (atomicAdd(ctr, 0) < nbk) __builtin_amdgcn_s_sleep(8);
    }
    __syncthreads();
    if (tid < 64) {
        int t = (tid < b) ? atomicAdd(&bsum[tid], 0) : 0;
#pragma unroll
        for (int o = 32; o; o >>= 1) t += __shfl_down(t, o);
        if (tid == 0) sbase = t;
    }
    __syncthreads();
    int pre = sbase + sd[tid] - s;
#pragma unroll
    for (int j = 0; j < 8; ++j) {
        int idx = base + j;
        if (idx < n) {
            off[idx] = pre;
            cur[idx] = pre;
            pre += loc[j];
        }
    }
    if (b == nbk - 1 && tid == 0) off[n] = sbase + sd[255];
}

// ---------------------------------------------------------------------------
// CSR fill: bin edge ids by source node.
// ---------------------------------------------------------------------------
__global__ void fill_kernel(const int* __restrict__ src, int* __restrict__ cur,
                            int* __restrict__ eid, int nedges) {
    int e = blockIdx.x * 256 + threadIdx.x;
    if (e < nedges) {
        int slot = atomicAdd(&cur[src[e]], 1);
        eid[slot] = e;
    }
}

// ---------------------------------------------------------------------------
// Fused gather + x-split + W1-prep.
//  Gather: ONE HALF-WAVE (32 lanes x 16B = 512B) per node -> one full row
//  per load instruction; 8-deep batch then 4/2/1 tail. Two independent
//  node-streams per wave. No cross-lane combine needed.
// ---------------------------------------------------------------------------
__global__ __launch_bounds__(256) void gather_split_kernel(
    const float* __restrict__ edge_attr, const int* __restrict__ eid,
    const int* __restrict__ off, unsigned int* __restrict__ aggp, int nnodes,
    const float* __restrict__ x, unsigned int* __restrict__ xp, int n4,
    const float* __restrict__ W1, unsigned short* __restrict__ Wh,
    unsigned short* __restrict__ Wl, int gblk, int sblk) {
    const int b = blockIdx.x;
    if (b < gblk) {
        int node = b * 8 + (threadIdx.x >> 5);   // half-wave per node
        if (node >= nnodes) return;
        const int c = threadIdx.x & 31;
        int i = off[node];
        const int e = off[node + 1];
        f32x4 acc = {0.f, 0.f, 0.f, 0.f};

        for (; i + 8 <= e; i += 8) {
            int r0 = eid[i + 0], r1 = eid[i + 1], r2 = eid[i + 2],
                r3 = eid[i + 3], r4 = eid[i + 4], r5 = eid[i + 5],
                r6 = eid[i + 6], r7 = eid[i + 7];
            f32x4 v0 = __builtin_nontemporal_load(
                (const f32x4*)(edge_attr + (size_t)r0 * D) + c);
            f32x4 v1 = __builtin_nontemporal_load(
                (const f32x4*)(edge_attr + (size_t)r1 * D) + c);
            f32x4 v2 = __builtin_nontemporal_load(
                (const f32x4*)(edge_attr + (size_t)r2 * D) + c);
            f32x4 v3 = __builtin_nontemporal_load(
                (const f32x4*)(edge_attr + (size_t)r3 * D) + c);
            f32x4 v4 = __builtin_nontemporal_load(
                (const f32x4*)(edge_attr + (size_t)r4 * D) + c);
            f32x4 v5 = __builtin_nontemporal_load(
                (const f32x4*)(edge_attr + (size_t)r5 * D) + c);
            f32x4 v6 = __builtin_nontemporal_load(
                (const f32x4*)(edge_attr + (size_t)r6 * D) + c);
            f32x4 v7 = __builtin_nontemporal_load(
                (const f32x4*)(edge_attr + (size_t)r7 * D) + c);
            acc += (v0 + v1) + (v2 + v3) + ((v4 + v5) + (v6 + v7));
        }
        if (i + 4 <= e) {
            int r0 = eid[i + 0], r1 = eid[i + 1], r2 = eid[i + 2],
                r3 = eid[i + 3];
            f32x4 v0 = __builtin_nontemporal_load(
                (const f32x4*)(edge_attr + (size_t)r0 * D) + c);
            f32x4 v1 = __builtin_nontemporal_load(
                (const f32x4*)(edge_attr + (size_t)r1 * D) + c);
            f32x4 v2 = __builtin_nontemporal_load(
                (const f32x4*)(edge_attr + (size_t)r2 * D) + c);
            f32x4 v3 = __builtin_nontemporal_load(
                (const f32x4*)(edge_attr + (size_t)r3 * D) + c);
            acc += (v0 + v1) + (v2 + v3);
            i += 4;
        }
        if (i + 2 <= e) {
            int r0 = eid[i + 0], r1 = eid[i + 1];
            f32x4 v0 = __builtin_nontemporal_load(
                (const f32x4*)(edge_attr + (size_t)r0 * D) + c);
            f32x4 v1 = __builtin_nontemporal_load(
                (const f32x4*)(edge_attr + (size_t)r1 * D) + c);
            acc += v0 + v1;
            i += 2;
        }
        if (i < e) {
            acc += __builtin_nontemporal_load(
                (const f32x4*)(edge_attr + (size_t)eid[i] * D) + c);
        }
        u32x4 p;
#pragma unroll
        for (int r = 0; r < 4; ++r) p[r] = packf(acc[r]);
        *((u32x4*)(aggp + (size_t)node * D) + c) = p;
    } else if (b < gblk + sblk) {
        int i = (b - gblk) * 256 + threadIdx.x;
        if (i < n4) {
            float4 v = ((const float4*)x)[i];
            uint4 p;
            p.x = packf(v.x);
            p.y = packf(v.y);
            p.z = packf(v.z);
            p.w = packf(v.w);
            ((uint4*)xp)[i] = p;
        }
    } else {
        int j = b - gblk - sblk;   // 0..127 output col
        int k = threadIdx.x;       // 0..255
        float w = W1[(size_t)k * D + j];
        unsigned int hi = bf16_rn(w);
        size_t o = (size_t)((k >> 3) * 128 + j) * 8 + (k & 7);
        Wh[o] = (unsigned short)hi;
        Wl[o] = (unsigned short)bf16_rn(w - bf16_f(hi));
    }
}

// ---------------------------------------------------------------------------
// Fold BN (batch stats) into next layer's W; frag-major split planes + bias.
// ---------------------------------------------------------------------------
__global__ void fold_kernel(const float* __restrict__ sum,
                            const float* __restrict__ sq,
                            const float* __restrict__ gamma,
                            const float* __restrict__ beta,
                            const float* __restrict__ W,
                            const float* __restrict__ b,
                            unsigned short* __restrict__ Wh,
                            unsigned short* __restrict__ Wl,
                            float* __restrict__ bf, float invM) {
    int j = blockIdx.x;
    int k = threadIdx.x;
    float mean = sum[k] * invM;
    float var = sq[k] * invM - mean * mean;
    float scale = gamma[k] * rsqrtf(var + 1e-5f);
    float shift = beta[k] - mean * scale;
    float w = W[k * D + j];
    float wf = scale * w;
    unsigned int hi = bf16_rn(wf);
    size_t o = (size_t)((k >> 3) * 128 + j) * 8 + (k & 7);
    Wh[o] = (unsigned short)hi;
    Wl[o] = (unsigned short)bf16_rn(wf - bf16_f(hi));
    float v = shift * w;
#pragma unroll
    for (int of = 32; of; of >>= 1) v += __shfl_down(v, of);
    __shared__ float ws2[2];
    if ((k & 63) == 0) ws2[k >> 6] = v;
    __syncthreads();
    if (k == 0) bf[j] = b[j] + ws2[0] + ws2[1];
}

// ---------------------------------------------------------------------------
// Split-bf16 MFMA GEMM, pre-split packed A (uint = hi|lo), frag-major W.
// 3 MFMAs per tile: Ah*Wh + Ah*Wl + Al*Wh. Block = 4 waves, BM = 128.
// K==256: k<128 from A0, k>=128 from A1 (implicit concat).
// C/D layout (m89): col = lane&15, row = (lane>>4)*4 + reg.
// ---------------------------------------------------------------------------
template <int K, bool SILU, bool STATS, bool PACKOUT>
__global__ __launch_bounds__(256, 2) void gemm_mfma(
    const unsigned int* __restrict__ A0, const unsigned int* __restrict__ A1,
    const unsigned short* __restrict__ Wh,
    const unsigned short* __restrict__ Wl,
    const float* __restrict__ bias, unsigned int* __restrict__ Cp,
    float* __restrict__ Cf, float* __restrict__ gsum,
    float* __restrict__ gsq, int M) {
    constexpr int NS = K / 32;
    const int tid = threadIdx.x;
    const int w = tid >> 6;
    const int l = tid & 63;
    const int lr = l & 15;
    const int lk = l >> 4;
    const int row0 = blockIdx.x * 128 + w * 32;

    facc acc[2][8];
#pragma unroll
    for (int rt = 0; rt < 2; ++rt)
#pragma unroll
        for (int ct = 0; ct < 8; ++ct)
#pragma unroll
            for (int r = 0; r < 4; ++r) acc[rt][ct][r] = 0.f;

    for (int s = 0; s < NS; ++s) {
        const int kb = s * 32 + lk * 8;
        bfrag ah[2], al[2];
#pragma unroll
        for (int rt = 0; rt < 2; ++rt) {
            const int arow = row0 + rt * 16 + lr;
            const unsigned int* As = A0;
            int kk = kb;
            if (K == 256 && s >= 4) { As = A1; kk = kb - 128; }
            u32x4 q0 = {0u, 0u, 0u, 0u}, q1 = {0u, 0u, 0u, 0u};
            if (arow < M) {
                const u32x4* p = (const u32x4*)(As + (size_t)arow * D + kk);
                q0 = p[0];
                q1 = p[1];
            }
            unsigned int ua[8] = {q0.x, q0.y, q0.z, q0.w,
                                  q1.x, q1.y, q1.z, q1.w};
            u32x4 uh, ul;
#pragma unroll
            for (int r = 0; r < 4; ++r) {
                uh[r] = __builtin_amdgcn_perm(ua[2 * r + 1], ua[2 * r],
                                              0x07060302u);
                ul[r] = __builtin_amdgcn_perm(ua[2 * r + 1], ua[2 * r],
                                              0x05040100u);
            }
            ah[rt] = __builtin_bit_cast(bfrag, uh);
            al[rt] = __builtin_bit_cast(bfrag, ul);
        }
        bfrag bh[8], bl[8];
        const int fb = (s * 4 + lk) * 128;
#pragma unroll
        for (int ct = 0; ct < 8; ++ct) {
            size_t o = (size_t)(fb + ct * 16 + lr) * 8;
            bh[ct] = *(const bfrag*)(Wh + o);
            bl[ct] = *(const bfrag*)(Wl + o);
        }
#pragma unroll
        for (int rt = 0; rt < 2; ++rt)
#pragma unroll
            for (int ct = 0; ct < 8; ++ct)
                acc[rt][ct] = mfma16(ah[rt], bh[ct], acc[rt][ct]);
#pragma unroll
        for (int rt = 0; rt < 2; ++rt)
#pragma unroll
            for (int ct = 0; ct < 8; ++ct)
                acc[rt][ct] = mfma16(ah[rt], bl[ct], acc[rt][ct]);
#pragma unroll
        for (int rt = 0; rt < 2; ++rt)
#pragma unroll
            for (int ct = 0; ct < 8; ++ct)
                acc[rt][ct] = mfma16(al[rt], bh[ct], acc[rt][ct]);
    }

    __shared__ float sred[2][4][128];
#pragma unroll
    for (int ct = 0; ct < 8; ++ct) {
        const int col = ct * 16 + lr;
        const float bj = bias[col];
        float s = 0.f, q = 0.f;
#pragma unroll
        for (int rt = 0; rt < 2; ++rt) {
            const int base = row0 + rt * 16 + lk * 4;
#pragma unroll
            for (int r = 0; r < 4; ++r) {
                int crow = base + r;
                if (crow < M) {
                    float v = acc[rt][ct][r] + bj;
                    if (SILU) v = v / (1.0f + __expf(-v));
                    if (PACKOUT) Cp[(size_t)crow * D + col] = packf(v);
                    else         Cf[(size_t)crow * D + col] = v;
                    if (STATS) { s += v; q += v * v; }
                }
            }
        }
        if (STATS) {
            s += __shfl_xor(s, 16);
            s += __shfl_xor(s, 32);
            q += __shfl_xor(q, 16);
            q += __shfl_xor(q, 32);
            if (lk == 0) {
                sred[0][w][col] = s;
                sred[1][w][col] = q;
            }
        }
    }
    if (STATS) {
        __syncthreads();
        if (tid < 128) {
            float v = sred[0][0][tid] + sred[0][1][tid] + sred[0][2][tid] +
                      sred[0][3][tid];
            unsafeAtomicAdd(&gsum[tid], v);
        } else {
            int c = tid - 128;
            float v = sred[1][0][c] + sred[1][1][c] + sred[1][2][c] +
                      sred[1][3][c];
            unsafeAtomicAdd(&gsq[c], v);
        }
    }
}

extern "C" void kernel_launch(void* const* d_in, const int* in_sizes, int n_in,
                              void* d_out, int out_size, void* d_ws,
                              size_t ws_size, hipStream_t stream) {
    const float* x     = (const float*)d_in[0];
    const int*   eidx  = (const int*)d_in[1];
    const float* eattr = (const float*)d_in[2];
    const float* W1  = (const float*)d_in[3];
    const float* b1  = (const float*)d_in[4];
    const float* g1  = (const float*)d_in[5];
    const float* be1 = (const float*)d_in[6];
    const float* W2  = (const float*)d_in[7];
    const float* b2  = (const float*)d_in[8];
    const float* g2  = (const float*)d_in[9];
    const float* be2 = (const float*)d_in[10];
    const float* W3  = (const float*)d_in[11];
    const float* b3  = (const float*)d_in[12];

    const int M = in_sizes[0] / D;   // 50000
    const int E = in_sizes[1] / 2;   // 600000
    const int* srcIdx = eidx;

    unsigned int* wsu = (unsigned int*)d_ws;
    unsigned int* aggp = wsu;                       // M*D packed
    unsigned int* xp   = aggp + (size_t)M * D;      // M*D
    unsigned int* h1p  = xp + (size_t)M * D;        // M*D
    unsigned int* h2p  = h1p + (size_t)M * D;       // M*D
    // zeroed region: counts[M], ctr[4], stats[4*D]  -> single memset
    int* counts = (int*)(h2p + (size_t)M * D);      // M
    int* ctr    = counts + M;                       // 4
    float* sum1 = (float*)(ctr + 4);                // D
    float* sq1  = sum1 + D;
    float* sum2 = sq1 + D;
    float* sq2  = sum2 + D;
    float* b2f  = sq2 + D;
    float* b3f  = b2f + D;
    int* off    = (int*)(b3f + D);                  // M+4
    int* cur    = off + M + 4;                      // M
    int* eid    = cur + M;                          // E
    int* bsum   = eid + E;                          // 64
    unsigned short* W1h = (unsigned short*)(bsum + 64);  // 128*256
    unsigned short* W1l = W1h + 256 * D;
    unsigned short* W2h = W1l + 256 * D;                 // 128*128
    unsigned short* W2l = W2h + D * D;
    unsigned short* W3h = W2l + D * D;
    unsigned short* W3l = W3h + D * D;

    float* out = (float*)d_out;

    (void)hipMemsetAsync(counts, 0, ((size_t)M + 4 + 4 * D) * sizeof(int),
                         stream);

    const int eblk = (E + 255) / 256;
    hist_kernel<<<eblk, 256, 0, stream>>>(srcIdx, counts, E);

    const int nbk = (M + SCHUNK - 1) / SCHUNK;   // 25 (co-resident)
    scanF_kernel<<<nbk, 256, 0, stream>>>(counts, bsum, ctr, off, cur, M, nbk);
    fill_kernel<<<eblk, 256, 0, stream>>>(srcIdx, cur, eid, E);

    const int gblk = (M + 7) / 8;
    const int sblk = (M * 32 + 255) / 256;
    gather_split_kernel<<<gblk + sblk + 128, 256, 0, stream>>>(
        eattr, eid, off, aggp, M, x, xp, M * 32, W1, W1h, W1l, gblk, sblk);

    int nblk = (M + 127) / 128;
    gemm_mfma<256, true, true, true><<<nblk, 256, 0, stream>>>(
        xp, aggp, W1h, W1l, b1, h1p, nullptr, sum1, sq1, M);
    fold_kernel<<<D, D, 0, stream>>>(sum1, sq1, g1, be1, W2, b2, W2h, W2l,
                                     b2f, 1.0f / (float)M);
    gemm_mfma<128, true, true, true><<<nblk, 256, 0, stream>>>(
        h1p, nullptr, W2h, W2l, b2f, h2p, nullptr, sum2, sq2, M);
    fold_kernel<<<D, D, 0, stream>>>(sum2, sq2, g2, be2, W3, b3, W3h, W3l,
                                     b3f, 1.0f / (float)M);
    gemm_mfma<128, false, false, false><<<nblk, 256, 0, stream>>>(
        h2p, nullptr, W3h, W3l, b3f, nullptr, out, nullptr, nullptr, M);
}